// Round 1
// baseline (201.563 us; speedup 1.0000x reference)
//
#include <hip/hip_runtime.h>

// RMAC: x[64, 2048, 16, 16] f32 -> f[64, 14*2048] L2-normalized per row.
// Level windows (H=W=16): l=1: 16x16 stride 1 -> 1 region
//                         l=2: 10x10 stride 4 -> 2x2 regions
//                         l=3:  8x8  stride 3 -> 3x3 regions
// Feature layout per batch: [l1 r0 | l2 r0..r3 | l3 r0..r8], each block C=2048,
// region r = i1*n + i2, value at (region_block*C + c).

constexpr int C    = 2048;
constexpr int NB   = 64;
constexpr int FEAT = 14 * C;       // 28672
constexpr float EPS = 1e-12f;

__global__ __launch_bounds__(256) void rmac_pool_kernel(
    const float* __restrict__ x, float* __restrict__ out,
    float* __restrict__ normbuf)
{
    const int img  = blockIdx.x * 256 + threadIdx.x;   // 0 .. NB*C-1
    const int b    = img >> 11;                        // / C
    const int c    = img & (C - 1);
    const float4* p = reinterpret_cast<const float4*>(x) + (size_t)img * 64;

    float acc1 = 0.f;
    float acc2[2][2] = {{0.f, 0.f}, {0.f, 0.f}};
    float acc3[3][3] = {{0.f, 0.f, 0.f}, {0.f, 0.f, 0.f}, {0.f, 0.f, 0.f}};

    #pragma unroll
    for (int y = 0; y < 16; ++y) {
        float4 q0 = p[y * 4 + 0];
        float4 q1 = p[y * 4 + 1];
        float4 q2 = p[y * 4 + 2];
        float4 q3 = p[y * 4 + 3];
        float v[16] = {q0.x, q0.y, q0.z, q0.w, q1.x, q1.y, q1.z, q1.w,
                       q2.x, q2.y, q2.z, q2.w, q3.x, q3.y, q3.z, q3.w};
        float pref[17];
        pref[0] = 0.f;
        #pragma unroll
        for (int k = 0; k < 16; ++k) pref[k + 1] = pref[k] + v[k];

        const float full = pref[16];
        const float c20  = pref[10];             // cols [0,10)
        const float c21  = pref[14] - pref[4];   // cols [4,14)
        const float c30  = pref[8];              // cols [0,8)
        const float c31  = pref[11] - pref[3];   // cols [3,11)
        const float c32  = pref[14] - pref[6];   // cols [6,14)

        acc1 += full;
        if (y < 10)            { acc2[0][0] += c20; acc2[0][1] += c21; }
        if (y >= 4 && y < 14)  { acc2[1][0] += c20; acc2[1][1] += c21; }
        if (y < 8)             { acc3[0][0] += c30; acc3[0][1] += c31; acc3[0][2] += c32; }
        if (y >= 3 && y < 11)  { acc3[1][0] += c30; acc3[1][1] += c31; acc3[1][2] += c32; }
        if (y >= 6 && y < 14)  { acc3[2][0] += c30; acc3[2][1] += c31; acc3[2][2] += c32; }
    }

    float f[14];
    f[0] = acc1 * (1.f / 256.f);
    #pragma unroll
    for (int i1 = 0; i1 < 2; ++i1)
        #pragma unroll
        for (int i2 = 0; i2 < 2; ++i2)
            f[1 + i1 * 2 + i2] = acc2[i1][i2] * (1.f / 100.f);
    #pragma unroll
    for (int i1 = 0; i1 < 3; ++i1)
        #pragma unroll
        for (int i2 = 0; i2 < 3; ++i2)
            f[5 + i1 * 3 + i2] = acc3[i1][i2] * (1.f / 64.f);

    float ss = 0.f;
    const size_t ob = (size_t)b * FEAT + c;
    #pragma unroll
    for (int k = 0; k < 14; ++k) {
        out[ob + (size_t)k * C] = f[k];   // coalesced across lanes (consecutive c)
        ss += f[k] * f[k];
    }

    // block reduction of sum-of-squares; b is uniform within a block (C % 256 == 0)
    #pragma unroll
    for (int off = 32; off; off >>= 1) ss += __shfl_down(ss, off, 64);
    __shared__ float red[4];
    const int lane = threadIdx.x & 63, wv = threadIdx.x >> 6;
    if (lane == 0) red[wv] = ss;
    __syncthreads();
    if (threadIdx.x == 0) atomicAdd(&normbuf[b], red[0] + red[1] + red[2] + red[3]);
}

__global__ __launch_bounds__(256) void rmac_scale_kernel(
    float* __restrict__ out, const float* __restrict__ normbuf)
{
    const int i = blockIdx.x * 256 + threadIdx.x;   // float4 index
    const int b = i / (FEAT / 4);                   // 7168 float4 per batch row
    const float s = 1.f / fmaxf(sqrtf(normbuf[b]), EPS);
    float4 v = reinterpret_cast<float4*>(out)[i];
    v.x *= s; v.y *= s; v.z *= s; v.w *= s;
    reinterpret_cast<float4*>(out)[i] = v;
}

extern "C" void kernel_launch(void* const* d_in, const int* in_sizes, int n_in,
                              void* d_out, int out_size, void* d_ws, size_t ws_size,
                              hipStream_t stream)
{
    const float* x = (const float*)d_in[0];
    float* out     = (float*)d_out;
    float* normbuf = (float*)d_ws;

    hipMemsetAsync(normbuf, 0, NB * sizeof(float), stream);

    rmac_pool_kernel<<<(NB * C) / 256, 256, 0, stream>>>(x, out, normbuf);

    const int n4 = (NB * FEAT) / 4;                 // 458752
    rmac_scale_kernel<<<n4 / 256, 256, 0, stream>>>(out, normbuf);
}

// Round 2
// 197.866 us; speedup vs baseline: 1.0187x; 1.0187x over previous
//
#include <hip/hip_runtime.h>

// RMAC: x[64, 2048, 16, 16] f32 -> f[64, 14*2048] L2-normalized per batch row.
// Windows (H=W=16): l1: 16x16 -> 1 region (/256); l2: 10x10 stride 4 -> 2x2,
// rows/cols [0,10),[4,14) (/100); l3: 8x8 stride 3 -> 3x3, [0,8),[3,11),[6,14) (/64).
// Feature k (0..13) at out[b*FEAT + k*C + c].
//
// Round-2 design: one image = 1 KiB = one fully-coalesced wave dwordx4 load.
// Stage 16 images/wave/iter into LDS (padded stride), lane (t=lane&15,q=lane>>4)
// computes rows 4q..4q+3 of image t, quarters combined via shfl_xor(16/32).
// Block out-tile [14][256] -> coalesced stores.

constexpr int C    = 2048;
constexpr int NB   = 64;
constexpr int FEAT = 14 * C;       // 28672
constexpr float EPS = 1e-12f;

constexpr int IMG_S4  = 65;            // float4 stride per image in LDS (1040 B: pad dodges worst conflicts)
constexpr int WAVE_S4 = 16 * IMG_S4;   // per-wave staging region

__global__ __launch_bounds__(256, 2) void rmac_pool_kernel(
    const float4* __restrict__ x4, float* __restrict__ out,
    float* __restrict__ normbuf)
{
    __shared__ float4 stage[4 * WAVE_S4];   // 66560 B
    __shared__ float  otile[14][256];       // 14336 B
    __shared__ float  red[4];

    const int tid  = threadIdx.x;
    const int lane = tid & 63;
    const int w    = tid >> 6;
    const int t    = lane & 15;   // image within stage
    const int q    = lane >> 4;   // row quarter

    const int blockImg = blockIdx.x * 256;
    float4* sw = stage + w * WAVE_S4;

    #pragma unroll 1
    for (int s = 0; s < 4; ++s) {
        const int imgBase = blockImg + w * 64 + s * 16;

        // 16 perfectly-coalesced 1 KiB loads (one whole image per instruction)
        float4 v[16];
        #pragma unroll
        for (int i = 0; i < 16; ++i)
            v[i] = x4[(size_t)(imgBase + i) * 64 + lane];
        #pragma unroll
        for (int i = 0; i < 16; ++i)
            sw[i * IMG_S4 + lane] = v[i];
        // same-wave LDS RAW: in-order DS pipe + compiler lgkmcnt — no barrier needed

        float rs[14];
        #pragma unroll
        for (int k = 0; k < 14; ++k) rs[k] = 0.f;

        const float4* img = sw + t * IMG_S4 + q * 16;   // rows 4q..4q+3
        #pragma unroll
        for (int r = 0; r < 4; ++r) {
            float4 a0 = img[r*4+0], a1 = img[r*4+1], a2 = img[r*4+2], a3 = img[r*4+3];
            float vv[16] = {a0.x,a0.y,a0.z,a0.w, a1.x,a1.y,a1.z,a1.w,
                            a2.x,a2.y,a2.z,a2.w, a3.x,a3.y,a3.z,a3.w};
            float pref[17]; pref[0] = 0.f;
            #pragma unroll
            for (int k2 = 0; k2 < 16; ++k2) pref[k2+1] = pref[k2] + vv[k2];

            const float full = pref[16];
            const float c20  = pref[10];             // cols [0,10)
            const float c21  = pref[14] - pref[4];   // cols [4,14)
            const float c30  = pref[8];              // cols [0,8)
            const float c31  = pref[11] - pref[3];   // cols [3,11)
            const float c32  = pref[14] - pref[6];   // cols [6,14)

            const int y = q * 4 + r;                 // lane-dependent -> predicated adds
            bool m;
            rs[0] += full;
            m = (y < 10);          rs[1]  += m ? c20 : 0.f; rs[2]  += m ? c21 : 0.f;
            m = (y >= 4 && y < 14);rs[3]  += m ? c20 : 0.f; rs[4]  += m ? c21 : 0.f;
            m = (y < 8);           rs[5]  += m ? c30 : 0.f; rs[6]  += m ? c31 : 0.f; rs[7]  += m ? c32 : 0.f;
            m = (y >= 3 && y < 11);rs[8]  += m ? c30 : 0.f; rs[9]  += m ? c31 : 0.f; rs[10] += m ? c32 : 0.f;
            m = (y >= 6 && y < 14);rs[11] += m ? c30 : 0.f; rs[12] += m ? c31 : 0.f; rs[13] += m ? c32 : 0.f;
        }

        // combine the 4 row-quarters (lanes t, t+16, t+32, t+48)
        #pragma unroll
        for (int k = 0; k < 14; ++k) {
            rs[k] += __shfl_xor(rs[k], 16, 64);
            rs[k] += __shfl_xor(rs[k], 32, 64);
        }

        const int col = w * 64 + s * 16 + t;
        #pragma unroll
        for (int k = 0; k < 14; ++k) {
            const float sc = (k == 0) ? (1.f/256.f) : (k < 5 ? (1.f/100.f) : (1.f/64.f));
            if ((k & 3) == q) otile[k][col] = rs[k] * sc;   // q-groups split the 14 writes
        }
    }
    __syncthreads();

    // epilogue: coalesced stores + sum-of-squares for the batch row
    const int img = blockImg + tid;          // block covers one b (C % 256 == 0)
    const int b   = img >> 11;
    const int c   = img & (C - 1);
    float ss = 0.f;
    #pragma unroll
    for (int k = 0; k < 14; ++k) {
        const float f = otile[k][tid];
        out[(size_t)b * FEAT + (size_t)k * C + c] = f;
        ss += f * f;
    }
    #pragma unroll
    for (int off = 32; off; off >>= 1) ss += __shfl_down(ss, off, 64);
    if (lane == 0) red[w] = ss;
    __syncthreads();
    if (tid == 0) atomicAdd(&normbuf[b], red[0] + red[1] + red[2] + red[3]);
}

__global__ __launch_bounds__(256) void rmac_scale_kernel(
    float* __restrict__ out, const float* __restrict__ normbuf)
{
    const int i = blockIdx.x * 256 + threadIdx.x;   // float4 index
    const int b = i / (FEAT / 4);                   // 7168 float4 per batch row
    const float s = 1.f / fmaxf(sqrtf(normbuf[b]), EPS);
    float4 v = reinterpret_cast<float4*>(out)[i];
    v.x *= s; v.y *= s; v.z *= s; v.w *= s;
    reinterpret_cast<float4*>(out)[i] = v;
}

extern "C" void kernel_launch(void* const* d_in, const int* in_sizes, int n_in,
                              void* d_out, int out_size, void* d_ws, size_t ws_size,
                              hipStream_t stream)
{
    const float4* x4 = (const float4*)d_in[0];
    float* out       = (float*)d_out;
    float* normbuf   = (float*)d_ws;

    hipMemsetAsync(normbuf, 0, NB * sizeof(float), stream);

    rmac_pool_kernel<<<(NB * C) / 256, 256, 0, stream>>>(x4, out, normbuf);

    const int n4 = (NB * FEAT) / 4;                 // 458752
    rmac_scale_kernel<<<n4 / 256, 256, 0, stream>>>(out, normbuf);
}

// Round 3
// 195.864 us; speedup vs baseline: 1.0291x; 1.0102x over previous
//
#include <hip/hip_runtime.h>

// RMAC: x[64, 2048, 16, 16] f32 -> f[64, 14*2048] L2-normalized per batch row.
// Windows (H=W=16): l1: 16x16 -> 1 region (/256); l2: 10x10 stride 4 -> 2x2,
// rows/cols [0,10),[4,14) (/100); l3: 8x8 stride 3 -> 3x3, [0,8),[3,11),[6,14) (/64).
// Feature k (0..13) at out[b*FEAT + k*C + c].
//
// Round-3: no d_ws / no memset / no atomics (norm kernel recomputes row ss);
// pool stages 8 images/wave/iter (47.6 KiB LDS -> 2 blocks/CU).

constexpr int C    = 2048;
constexpr int NB   = 64;
constexpr int FEAT = 14 * C;       // 28672
constexpr float EPS = 1e-12f;

constexpr int IMG_S4  = 65;           // float4 stride per image in LDS (1040 B)
constexpr int WAVE_S4 = 8 * IMG_S4;   // 8 images staged per wave per iter

__global__ __launch_bounds__(256, 2) void rmac_pool_kernel(
    const float4* __restrict__ x4, float* __restrict__ out)
{
    __shared__ float4 stage[4 * WAVE_S4];   // 33280 B
    __shared__ float  otile[14][256];       // 14336 B

    const int tid  = threadIdx.x;
    const int lane = tid & 63;
    const int w    = tid >> 6;
    const int t    = lane & 7;    // image within stage
    const int o    = lane >> 3;   // row pair 0..7 (rows 2o, 2o+1)

    const int blockImg = blockIdx.x * 256;
    float4* sw = stage + w * WAVE_S4;

    #pragma unroll 1
    for (int s = 0; s < 8; ++s) {
        const int imgBase = blockImg + w * 64 + s * 8;

        // 8 perfectly-coalesced 1 KiB loads (one whole image per instruction)
        float4 v[8];
        #pragma unroll
        for (int i = 0; i < 8; ++i)
            v[i] = x4[(size_t)(imgBase + i) * 64 + lane];
        #pragma unroll
        for (int i = 0; i < 8; ++i)
            sw[i * IMG_S4 + lane] = v[i];
        // same-wave LDS RAW: in-order DS pipe + compiler lgkmcnt — no barrier needed

        float rs[14];
        #pragma unroll
        for (int k = 0; k < 14; ++k) rs[k] = 0.f;

        const float4* img = sw + t * IMG_S4 + o * 8;   // rows 2o, 2o+1
        #pragma unroll
        for (int r = 0; r < 2; ++r) {
            float4 a0 = img[r*4+0], a1 = img[r*4+1], a2 = img[r*4+2], a3 = img[r*4+3];
            float vv[16] = {a0.x,a0.y,a0.z,a0.w, a1.x,a1.y,a1.z,a1.w,
                            a2.x,a2.y,a2.z,a2.w, a3.x,a3.y,a3.z,a3.w};
            float pref[17]; pref[0] = 0.f;
            #pragma unroll
            for (int k2 = 0; k2 < 16; ++k2) pref[k2+1] = pref[k2] + vv[k2];

            const float full = pref[16];
            const float c20  = pref[10];             // cols [0,10)
            const float c21  = pref[14] - pref[4];   // cols [4,14)
            const float c30  = pref[8];              // cols [0,8)
            const float c31  = pref[11] - pref[3];   // cols [3,11)
            const float c32  = pref[14] - pref[6];   // cols [6,14)

            const int y = o * 2 + r;                 // lane-dependent -> predicated adds
            bool m;
            rs[0] += full;
            m = (y < 10);          rs[1]  += m ? c20 : 0.f; rs[2]  += m ? c21 : 0.f;
            m = (y >= 4 && y < 14);rs[3]  += m ? c20 : 0.f; rs[4]  += m ? c21 : 0.f;
            m = (y < 8);           rs[5]  += m ? c30 : 0.f; rs[6]  += m ? c31 : 0.f; rs[7]  += m ? c32 : 0.f;
            m = (y >= 3 && y < 11);rs[8]  += m ? c30 : 0.f; rs[9]  += m ? c31 : 0.f; rs[10] += m ? c32 : 0.f;
            m = (y >= 6 && y < 14);rs[11] += m ? c30 : 0.f; rs[12] += m ? c31 : 0.f; rs[13] += m ? c32 : 0.f;
        }

        // combine the 8 row-pairs (lanes t, t+8, ..., t+56)
        #pragma unroll
        for (int k = 0; k < 14; ++k) {
            rs[k] += __shfl_xor(rs[k], 8, 64);
            rs[k] += __shfl_xor(rs[k], 16, 64);
            rs[k] += __shfl_xor(rs[k], 32, 64);
        }

        const int col = w * 64 + s * 8 + t;
        #pragma unroll
        for (int k = 0; k < 14; ++k) {
            const float sc = (k == 0) ? (1.f/256.f) : (k < 5 ? (1.f/100.f) : (1.f/64.f));
            if ((k & 7) == o) otile[k][col] = rs[k] * sc;   // o-groups split the 14 writes
        }
    }
    __syncthreads();

    // coalesced feature stores (block covers 256 consecutive c of one b)
    const int img = blockImg + tid;
    const int b   = img >> 11;
    const int c   = img & (C - 1);
    #pragma unroll
    for (int k = 0; k < 14; ++k)
        out[(size_t)b * FEAT + (size_t)k * C + c] = otile[k][tid];
}

// One block per batch row: recompute ss, scale in place. Row data is L2/L3-hot.
__global__ __launch_bounds__(1024) void rmac_norm_kernel(float* __restrict__ out)
{
    const int b   = blockIdx.x;
    const int tid = threadIdx.x;
    float4* row = reinterpret_cast<float4*>(out + (size_t)b * FEAT);  // 7168 float4

    float4 v[7];
    float ss = 0.f;
    #pragma unroll
    for (int j = 0; j < 7; ++j) {
        v[j] = row[tid + j * 1024];
        ss += v[j].x*v[j].x + v[j].y*v[j].y + v[j].z*v[j].z + v[j].w*v[j].w;
    }

    #pragma unroll
    for (int off = 32; off; off >>= 1) ss += __shfl_down(ss, off, 64);
    __shared__ float red[16];
    const int lane = tid & 63, w = tid >> 6;
    if (lane == 0) red[w] = ss;
    __syncthreads();
    float tot = 0.f;
    #pragma unroll
    for (int i = 0; i < 16; ++i) tot += red[i];   // broadcast reads, no conflicts

    const float s = 1.f / fmaxf(sqrtf(tot), EPS);
    #pragma unroll
    for (int j = 0; j < 7; ++j) {
        v[j].x *= s; v[j].y *= s; v[j].z *= s; v[j].w *= s;
        row[tid + j * 1024] = v[j];
    }
}

extern "C" void kernel_launch(void* const* d_in, const int* in_sizes, int n_in,
                              void* d_out, int out_size, void* d_ws, size_t ws_size,
                              hipStream_t stream)
{
    const float4* x4 = (const float4*)d_in[0];
    float* out       = (float*)d_out;

    rmac_pool_kernel<<<(NB * C) / 256, 256, 0, stream>>>(x4, out);
    rmac_norm_kernel<<<NB, 1024, 0, stream>>>(out);
}